// Round 9
// baseline (9601.038 us; speedup 1.0000x reference)
//
#include <hip/hip_runtime.h>
#include <math.h>

#define S_  256
#define B_  64
#define E_  512
#define H_  512
#define G4_ 2048   // 4*H
#define NL_ 4
#define E4_ 128    // H/4

typedef __attribute__((ext_vector_type(8))) short bf16x8;
typedef __attribute__((ext_vector_type(4))) float f32x4;

__device__ __forceinline__ float fsigmoid(float x) {
    return 1.0f / (1.0f + __expf(-x));
}
__device__ __forceinline__ float ftanh_(float x) {
    x = fminf(fmaxf(x, -15.0f), 15.0f);
    float e = __expf(2.0f * x);
    return (e - 1.0f) / (e + 1.0f);
}
__device__ __forceinline__ ushort f2bf(float x) {   // RNE float->bf16
    unsigned u = __float_as_uint(x);
    return (ushort)((u + 0x7FFFu + ((u >> 16) & 1u)) >> 16);
}
__device__ __forceinline__ float bf2f(ushort u) {
    return __uint_as_float((unsigned)u << 16);
}

// ---------------------------------------------------------------------------
// h-slab layout (bf16 hi/lo planes, B-frag friendly):
//   hb[t][grp(8)][plane(2: hi,lo)][cc(16)][k(512)] ushort
//   grp = bblk*2 + dir;  cc = b&15;  k = j.
// Consumer B-frag: lane l, slot ks reads 8 ushorts at cc*512 + (l>>4)*8 + ks*32.
// ---------------------------------------------------------------------------
#define SLAB_ ((size_t)16 * 512)          // one plane, ushorts
__device__ __forceinline__ size_t slab_off(int t, int grp) {
    return ((size_t)(t * 8 + grp) * 2) * SLAB_;
}

// A-tile loader: T4=0 -> row-major [M][E]; T4=1 -> reconstruct hF+hB from slabs
template<int T4>
__device__ __forceinline__ float4 ldA(const float* __restrict__ A,
                                      const ushort* __restrict__ hb,
                                      int m, int kk) {
    if constexpr (T4) {
        int t = m >> 6, b = m & 63, cc = b & 15, bb = b >> 4;
        size_t e = (size_t)cc * 512 + kk;
        const ushort* pF = hb + slab_off(t, bb * 2 + 0) + e;
        const ushort* pB = hb + slab_off(t, bb * 2 + 1) + e;
        ushort4 hF = *(const ushort4*)pF;
        ushort4 lF = *(const ushort4*)(pF + SLAB_);
        ushort4 hB = *(const ushort4*)pB;
        ushort4 lB = *(const ushort4*)(pB + SLAB_);
        return make_float4(
            bf2f(hF.x) + bf2f(lF.x) + bf2f(hB.x) + bf2f(lB.x),
            bf2f(hF.y) + bf2f(lF.y) + bf2f(hB.y) + bf2f(lB.y),
            bf2f(hF.z) + bf2f(lF.z) + bf2f(hB.z) + bf2f(lB.z),
            bf2f(hF.w) + bf2f(lF.w) + bf2f(hB.w) + bf2f(lB.w));
    } else {
        return *(const float4*)&A[(size_t)m * E_ + kk];
    }
}

// pre[t][g][b] = sum_k In[t*64+b][k] * Wi[g][k] + bias[g]
#define BM_ 128
#define BN_ 128
#define BK_ 16

template<int T4>
__global__ __launch_bounds__(256) void pre_gemm_k(
    const float* __restrict__ In,
    const ushort* __restrict__ hb,
    const float* __restrict__ Wi,
    const float* __restrict__ bias,
    float* __restrict__ pre)
{
    __shared__ float As[BK_][BM_ + 4];
    __shared__ float Bs[BK_][BN_ + 4];

    const int tid = threadIdx.x;
    const int bx  = blockIdx.x;          // 0..2047
    const int m0  = (bx >> 4) * BM_;
    const int n0  = (bx & 15) * BN_;
    const int tx  = tid & 15;
    const int ty  = tid >> 4;
    const int lr  = tid >> 2;            // 0..63
    const int lc  = (tid & 3) << 2;      // 0,4,8,12

    float acc[8][8];
#pragma unroll
    for (int i = 0; i < 8; ++i)
#pragma unroll
        for (int j = 0; j < 8; ++j) acc[i][j] = 0.0f;

    for (int k0 = 0; k0 < E_; k0 += BK_) {
        float4 a0 = ldA<T4>(In, hb, m0 + lr,      k0 + lc);
        float4 a1 = ldA<T4>(In, hb, m0 + lr + 64, k0 + lc);
        float4 b0 = *(const float4*)&Wi[(size_t)(n0 + lr) * E_ + k0 + lc];
        float4 b1 = *(const float4*)&Wi[(size_t)(n0 + lr + 64) * E_ + k0 + lc];
        __syncthreads();
        As[lc + 0][lr] = a0.x; As[lc + 1][lr] = a0.y; As[lc + 2][lr] = a0.z; As[lc + 3][lr] = a0.w;
        As[lc + 0][lr + 64] = a1.x; As[lc + 1][lr + 64] = a1.y; As[lc + 2][lr + 64] = a1.z; As[lc + 3][lr + 64] = a1.w;
        Bs[lc + 0][lr] = b0.x; Bs[lc + 1][lr] = b0.y; Bs[lc + 2][lr] = b0.z; Bs[lc + 3][lr] = b0.w;
        Bs[lc + 0][lr + 64] = b1.x; Bs[lc + 1][lr + 64] = b1.y; Bs[lc + 2][lr + 64] = b1.z; Bs[lc + 3][lr + 64] = b1.w;
        __syncthreads();
#pragma unroll
        for (int kk = 0; kk < BK_; ++kk) {
            float4 av0 = *(const float4*)&As[kk][ty * 8];
            float4 av1 = *(const float4*)&As[kk][ty * 8 + 4];
            float4 bv0 = *(const float4*)&Bs[kk][tx * 8];
            float4 bv1 = *(const float4*)&Bs[kk][tx * 8 + 4];
            float a[8] = {av0.x, av0.y, av0.z, av0.w, av1.x, av1.y, av1.z, av1.w};
            float b[8] = {bv0.x, bv0.y, bv0.z, bv0.w, bv1.x, bv1.y, bv1.z, bv1.w};
#pragma unroll
            for (int i = 0; i < 8; ++i)
#pragma unroll
                for (int j = 0; j < 8; ++j)
                    acc[i][j] = fmaf(a[i], b[j], acc[i][j]);
        }
    }

#pragma unroll
    for (int i = 0; i < 8; ++i) {
        int m  = m0 + ty * 8 + i;
        int tt = m >> 6;
        int bb = m & 63;
#pragma unroll
        for (int j = 0; j < 8; ++j) {
            int n = n0 + tx * 8 + j;
            pre[((size_t)tt * G4_ + n) * B_ + bb] = acc[i][j] + bias[n];
        }
    }
}

// ---------------------------------------------------------------------------
// Wh (fp32 [2048][512]) -> hi/lo bf16 pair in MFMA-A-fragment order (as R7/R8):
//   idx[wgin][w][ks][lane][e]; lane l: r=l&15 -> (g=r&3, j=wgin*16+w*4+(r>>2)),
//   k = ks*32 + (l>>4)*8 + e.
// ---------------------------------------------------------------------------
__global__ __launch_bounds__(256) void whb_k(
    const float* __restrict__ Wh,
    ushort* __restrict__ WhH, ushort* __restrict__ WhL)
{
    int i = blockIdx.x * 256 + threadIdx.x;       // 1,048,576
    int e = i & 7, l = (i >> 3) & 63, ks = (i >> 9) & 15;
    int w = (i >> 13) & 3, wgin = i >> 15;
    int r = l & 15, g = r & 3, j = wgin * 16 + w * 4 + (r >> 2);
    int k = ks * 32 + ((l >> 4) << 3) + e;
    float x = Wh[(size_t)(g * H_ + j) * H_ + k];
    ushort hi = f2bf(x);
    WhH[i] = hi;
    WhL[i] = f2bf(x - bf2f(hi));
}

// ---------------------------------------------------------------------------
// Persistent recurrence v7: producer-side hi/lo conversion, LDS-free B-frags.
// grp = bid&7 (one group per XCD under %8 round-robin -> h slab stays in the
// local L2; perf-only assumption), wgin = bid>>3. Weights in VGPRs (R8).
// Per step: poll -> 32 global b128 B-frag loads (16 ks x hi/lo, L1/L2-hot)
// -> 48 MFMAs (3 indep chains) -> lane-local gates/c -> publish packed hi/lo
// (shfl_xor lane-pair -> 2 uint32 write-through stores) -> drain -> signal.
// No LDS. Protocol (first-touch slabs + relaxed agent cnt) proven R4-R8.
// ---------------------------------------------------------------------------
__global__ __launch_bounds__(256, 1) void lstm_persist_k(
    const float* __restrict__ pre,    // [S][G4][B]
    const ushort* __restrict__ WhH,   // frag-ordered bf16 hi
    const ushort* __restrict__ WhL,   // frag-ordered bf16 lo
    ushort* __restrict__ hb,          // h slabs [S][8][2][16][512]
    unsigned* __restrict__ cnt)       // [8][S][16], zeroed before launch
{
    const int tid  = threadIdx.x;
    const int grp  = blockIdx.x & 7;             // sync domain (XCD-local)
    const int wgin = blockIdx.x >> 3;            // 0..31 j-slice
    const int dir  = grp & 1;
    const int bblk = grp >> 1;
    const int w    = tid >> 6;                   // wave / row-tile
    const int l    = tid & 63;
    const int ch   = l & 15;
    const int jloc = l >> 4;                     // 0..3
    const int j    = wgin * 16 + w * 4 + jloc;
    const int b    = bblk * 16 + ch;

    unsigned* mycnt = &cnt[((size_t)grp * S_) * 16];
    const ushort* wbaseH = WhH + ((size_t)(wgin * 4 + w) << 13) + (l << 3);
    const ushort* wbaseL = WhL + ((size_t)(wgin * 4 + w) << 13) + (l << 3);

    // B-frag lane offset within a plane: cc*512 + (l>>4)*8  (+ ks*32 per slot)
    const int fragoff = ch * 512 + (jloc << 3);

    // preload this wave's full weight slice into registers
    bf16x8 wH[16], wL[16];
#pragma unroll
    for (int ks = 0; ks < 16; ++ks) {
        wH[ks] = *(const bf16x8*)(wbaseH + (ks << 9));
        wL[ks] = *(const bf16x8*)(wbaseL + (ks << 9));
    }

    float c = 0.0f;

    for (int t = 0; t < S_; ++t) {
        const int tf = dir ? (S_ - 1 - t) : t;

        // own (j,b) pre values for all 4 gates -> MFMA C-in (issued pre-poll)
        f32x4 acc;
#pragma unroll
        for (int g = 0; g < 4; ++g)
            acc[g] = pre[((size_t)tf * G4_ + g * H_ + j) * B_ + b];

        if (t > 0) {
            // group barrier: poll (relaxed agent, no cache maintenance)
            unsigned guard = 0;
            while (__hip_atomic_load(&mycnt[(size_t)(t - 1) * 16], __ATOMIC_RELAXED,
                                     __HIP_MEMORY_SCOPE_AGENT) < 32u) {
                if (++guard > (1u << 18)) break;   // fail visibly, don't hang
            }

            const int tfp = dir ? (tf + 1) : (tf - 1);
            const ushort* sh = hb + slab_off(tfp, grp) + fragoff;   // hi plane
            const ushort* sl = sh + SLAB_;                          // lo plane

            // 48 MFMAs over K=512, 3 independent chains; B-frags straight
            // from global (first-touch per t -> no stale caches)
            f32x4 aB = {0.f, 0.f, 0.f, 0.f}, aC = {0.f, 0.f, 0.f, 0.f};
#pragma unroll
            for (int ks = 0; ks < 16; ++ks) {
                bf16x8 bh = *(const bf16x8*)(sh + (ks << 5));
                bf16x8 bl = *(const bf16x8*)(sl + (ks << 5));
                acc = __builtin_amdgcn_mfma_f32_16x16x32_bf16(wH[ks], bh, acc, 0, 0, 0);
                aB  = __builtin_amdgcn_mfma_f32_16x16x32_bf16(wH[ks], bl, aB, 0, 0, 0);
                aC  = __builtin_amdgcn_mfma_f32_16x16x32_bf16(wL[ks], bh, aC, 0, 0, 0);
            }
#pragma unroll
            for (int g = 0; g < 4; ++g) acc[g] += aB[g] + aC[g];
        }

        // gates (order i,f,o,g), fully lane-local
        float si = fsigmoid(acc[0]);
        float sf = fsigmoid(acc[1]);
        float so = fsigmoid(acc[2]);
        float tg = ftanh_(acc[3]);
        c = fmaf(sf, c, si * tg);
        float h = so * ftanh_(c);

        // publish h as hi/lo bf16, packed k-pairs via lane partner (j ^ 1)
        ushort hi = f2bf(h);
        ushort lo = f2bf(h - bf2f(hi));
        unsigned hv = ((unsigned)lo << 16) | hi;
        unsigned pv = (unsigned)__shfl_xor((int)hv, 16);   // partner: j^1
        if ((jloc & 1) == 0) {
            unsigned hiPair = (hv & 0xFFFFu) | (pv << 16);
            unsigned loPair = (hv >> 16) | (pv & 0xFFFF0000u);
            unsigned* shW = (unsigned*)(hb + slab_off(tf, grp));
            size_t ui = (size_t)ch * 256 + (j >> 1);
            __hip_atomic_store(&shW[ui], hiPair, __ATOMIC_RELAXED,
                               __HIP_MEMORY_SCOPE_AGENT);
            __hip_atomic_store(&shW[(SLAB_ >> 1) + ui], loPair, __ATOMIC_RELAXED,
                               __HIP_MEMORY_SCOPE_AGENT);
        }
        asm volatile("s_waitcnt vmcnt(0)" ::: "memory");
        __syncthreads();
        if (tid == 0)
            __hip_atomic_fetch_add(&mycnt[(size_t)t * 16], 1u,
                                   __ATOMIC_RELAXED, __HIP_MEMORY_SCOPE_AGENT);
    }
}

// out[t][b][e] = (hiF+loF) + (hiB+loB) from slabs
__global__ __launch_bounds__(256) void t4_to_row_k(
    const ushort* __restrict__ hb, float* __restrict__ out)
{
    int i  = blockIdx.x * 256 + threadIdx.x;   // 2,097,152 float4 units
    int e4 = i & (E4_ - 1);
    int b  = (i >> 7) & 63;
    int t  = i >> 13;
    int cc = b & 15, bb = b >> 4;
    size_t e = (size_t)cc * 512 + e4 * 4;
    const ushort* pF = hb + slab_off(t, bb * 2 + 0) + e;
    const ushort* pB = hb + slab_off(t, bb * 2 + 1) + e;
    ushort4 hF = *(const ushort4*)pF;
    ushort4 lF = *(const ushort4*)(pF + SLAB_);
    ushort4 hB = *(const ushort4*)pB;
    ushort4 lB = *(const ushort4*)(pB + SLAB_);
    float4 v = make_float4(
        bf2f(hF.x) + bf2f(lF.x) + bf2f(hB.x) + bf2f(lB.x),
        bf2f(hF.y) + bf2f(lF.y) + bf2f(hB.y) + bf2f(lB.y),
        bf2f(hF.z) + bf2f(lF.z) + bf2f(hB.z) + bf2f(lB.z),
        bf2f(hF.w) + bf2f(lF.w) + bf2f(hB.w) + bf2f(lB.w));
    *(float4*)&out[((size_t)(t * B_ + b)) * E_ + e4 * 4] = v;
}

// tail [b][j] = h_fwd(tf=255) + h_bwd(tf=0)
__global__ __launch_bounds__(256) void tail_k(
    const ushort* __restrict__ hb, float* __restrict__ out2)
{
    int i = blockIdx.x * 256 + threadIdx.x;   // 32768
    int b = i >> 9, j = i & 511;
    int cc = b & 15, bb = b >> 4;
    const ushort* pF = hb + slab_off(255, bb * 2 + 0) + (size_t)cc * 512 + j;
    const ushort* pB = hb + slab_off(0,   bb * 2 + 1) + (size_t)cc * 512 + j;
    out2[i] = bf2f(pF[0]) + bf2f(pF[SLAB_]) + bf2f(pB[0]) + bf2f(pB[SLAB_]);
}

// ---------------------------------------------------------------------------
// Workspace (bytes):
//   pre : 128 MiB (fp32)      hb  : 64 MiB (bf16 hi/lo slabs, [S][8][2][16][512])
//   cnt : 128 KiB             WhH/WhL : 2+2 MiB
// total ~196.2 MiB
// ---------------------------------------------------------------------------
extern "C" void kernel_launch(void* const* d_in, const int* in_sizes, int n_in,
                              void* d_out, int out_size, void* d_ws, size_t ws_size,
                              hipStream_t stream) {
    const float* x    = (const float*)d_in[0];
    const float* Wi   = (const float*)d_in[1];
    const float* Wh   = (const float*)d_in[2];
    const float* bias = (const float*)d_in[3];
    float* out = (float*)d_out;

    float* ws  = (float*)d_ws;
    float* pre = ws;
    ushort* hb = (ushort*)(pre + (size_t)S_ * G4_ * B_);        // 33.5M ushorts
    unsigned* cnt = (unsigned*)(hb + (size_t)S_ * 8 * 2 * SLAB_);
    ushort* WhH = (ushort*)(cnt + (size_t)8 * S_ * 16);
    ushort* WhL = WhH + (size_t)1024 * 1024;

    for (int l = 0; l < NL_; ++l) {
        const float* wi_l = Wi + (size_t)l * G4_ * E_;
        const float* wh_l = Wh + (size_t)l * G4_ * H_;
        const float* b_l  = bias + (size_t)l * G4_;
        if (l == 0) pre_gemm_k<0><<<2048, 256, 0, stream>>>(x,  hb, wi_l, b_l, pre);
        else        pre_gemm_k<1><<<2048, 256, 0, stream>>>(x,  hb, wi_l, b_l, pre);
        whb_k<<<4096, 256, 0, stream>>>(wh_l, WhH, WhL);
        hipMemsetAsync(cnt, 0, (size_t)8 * S_ * 16 * sizeof(unsigned), stream);
        lstm_persist_k<<<256, 256, 0, stream>>>(pre, WhH, WhL, hb, cnt);
    }
    t4_to_row_k<<<8192, 256, 0, stream>>>(hb, out);
    tail_k<<<128, 256, 0, stream>>>(hb, out + (size_t)S_ * B_ * H_);
}

// Round 10
// 5814.368 us; speedup vs baseline: 1.6513x; 1.6513x over previous
//
#include <hip/hip_runtime.h>
#include <math.h>

#define S_  256
#define B_  64
#define E_  512
#define H_  512
#define G4_ 2048   // 4*H
#define NL_ 4
#define E4_ 128    // H/4

typedef __attribute__((ext_vector_type(8))) short bf16x8;
typedef __attribute__((ext_vector_type(4))) float f32x4;

__device__ __forceinline__ float fsigmoid(float x) {
    return 1.0f / (1.0f + __expf(-x));
}
__device__ __forceinline__ float ftanh_(float x) {
    x = fminf(fmaxf(x, -15.0f), 15.0f);
    float e = __expf(2.0f * x);
    return (e - 1.0f) / (e + 1.0f);
}
__device__ __forceinline__ ushort f2bf(float x) {   // RNE float->bf16
    unsigned u = __float_as_uint(x);
    return (ushort)((u + 0x7FFFu + ((u >> 16) & 1u)) >> 16);
}
__device__ __forceinline__ float bf2f(ushort u) {
    return __uint_as_float((unsigned)u << 16);
}

// async global->LDS, 16B per lane (lane i lands at lptr + i*16)
__device__ __forceinline__ void dma16(const ushort* g, ushort* l) {
    __builtin_amdgcn_global_load_lds(
        (const __attribute__((address_space(1))) unsigned*)g,
        (__attribute__((address_space(3))) unsigned*)l, 16, 0, 0);
}

// ---------------------------------------------------------------------------
// h-slab layout (bf16 hi/lo planes):
//   hb[t][grp(8)][plane(2: hi,lo)][cc(16)][k(512)] ushort
//   grp = bblk*2 + dir;  cc = b&15;  k = j.
// ---------------------------------------------------------------------------
#define SLAB_ ((size_t)16 * 512)          // one plane, ushorts
__device__ __forceinline__ size_t slab_off(int t, int grp) {
    return ((size_t)(t * 8 + grp) * 2) * SLAB_;
}

// A-tile loader: T4=0 -> row-major [M][E]; T4=1 -> reconstruct hF+hB from slabs
template<int T4>
__device__ __forceinline__ float4 ldA(const float* __restrict__ A,
                                      const ushort* __restrict__ hb,
                                      int m, int kk) {
    if constexpr (T4) {
        int t = m >> 6, b = m & 63, cc = b & 15, bb = b >> 4;
        size_t e = (size_t)cc * 512 + kk;
        const ushort* pF = hb + slab_off(t, bb * 2 + 0) + e;
        const ushort* pB = hb + slab_off(t, bb * 2 + 1) + e;
        ushort4 hF = *(const ushort4*)pF;
        ushort4 lF = *(const ushort4*)(pF + SLAB_);
        ushort4 hB = *(const ushort4*)pB;
        ushort4 lB = *(const ushort4*)(pB + SLAB_);
        return make_float4(
            bf2f(hF.x) + bf2f(lF.x) + bf2f(hB.x) + bf2f(lB.x),
            bf2f(hF.y) + bf2f(lF.y) + bf2f(hB.y) + bf2f(lB.y),
            bf2f(hF.z) + bf2f(lF.z) + bf2f(hB.z) + bf2f(lB.z),
            bf2f(hF.w) + bf2f(lF.w) + bf2f(hB.w) + bf2f(lB.w));
    } else {
        return *(const float4*)&A[(size_t)m * E_ + kk];
    }
}

// pre[t][g][b] = sum_k In[t*64+b][k] * Wi[g][k] + bias[g]
#define BM_ 128
#define BN_ 128
#define BK_ 16

template<int T4>
__global__ __launch_bounds__(256) void pre_gemm_k(
    const float* __restrict__ In,
    const ushort* __restrict__ hb,
    const float* __restrict__ Wi,
    const float* __restrict__ bias,
    float* __restrict__ pre)
{
    __shared__ float As[BK_][BM_ + 4];
    __shared__ float Bs[BK_][BN_ + 4];

    const int tid = threadIdx.x;
    const int bx  = blockIdx.x;          // 0..2047
    const int m0  = (bx >> 4) * BM_;
    const int n0  = (bx & 15) * BN_;
    const int tx  = tid & 15;
    const int ty  = tid >> 4;
    const int lr  = tid >> 2;            // 0..63
    const int lc  = (tid & 3) << 2;      // 0,4,8,12

    float acc[8][8];
#pragma unroll
    for (int i = 0; i < 8; ++i)
#pragma unroll
        for (int j = 0; j < 8; ++j) acc[i][j] = 0.0f;

    for (int k0 = 0; k0 < E_; k0 += BK_) {
        float4 a0 = ldA<T4>(In, hb, m0 + lr,      k0 + lc);
        float4 a1 = ldA<T4>(In, hb, m0 + lr + 64, k0 + lc);
        float4 b0 = *(const float4*)&Wi[(size_t)(n0 + lr) * E_ + k0 + lc];
        float4 b1 = *(const float4*)&Wi[(size_t)(n0 + lr + 64) * E_ + k0 + lc];
        __syncthreads();
        As[lc + 0][lr] = a0.x; As[lc + 1][lr] = a0.y; As[lc + 2][lr] = a0.z; As[lc + 3][lr] = a0.w;
        As[lc + 0][lr + 64] = a1.x; As[lc + 1][lr + 64] = a1.y; As[lc + 2][lr + 64] = a1.z; As[lc + 3][lr + 64] = a1.w;
        Bs[lc + 0][lr] = b0.x; Bs[lc + 1][lr] = b0.y; Bs[lc + 2][lr] = b0.z; Bs[lc + 3][lr] = b0.w;
        Bs[lc + 0][lr + 64] = b1.x; Bs[lc + 1][lr + 64] = b1.y; Bs[lc + 2][lr + 64] = b1.z; Bs[lc + 3][lr + 64] = b1.w;
        __syncthreads();
#pragma unroll
        for (int kk = 0; kk < BK_; ++kk) {
            float4 av0 = *(const float4*)&As[kk][ty * 8];
            float4 av1 = *(const float4*)&As[kk][ty * 8 + 4];
            float4 bv0 = *(const float4*)&Bs[kk][tx * 8];
            float4 bv1 = *(const float4*)&Bs[kk][tx * 8 + 4];
            float a[8] = {av0.x, av0.y, av0.z, av0.w, av1.x, av1.y, av1.z, av1.w};
            float b[8] = {bv0.x, bv0.y, bv0.z, bv0.w, bv1.x, bv1.y, bv1.z, bv1.w};
#pragma unroll
            for (int i = 0; i < 8; ++i)
#pragma unroll
                for (int j = 0; j < 8; ++j)
                    acc[i][j] = fmaf(a[i], b[j], acc[i][j]);
        }
    }

#pragma unroll
    for (int i = 0; i < 8; ++i) {
        int m  = m0 + ty * 8 + i;
        int tt = m >> 6;
        int bb = m & 63;
#pragma unroll
        for (int j = 0; j < 8; ++j) {
            int n = n0 + tx * 8 + j;
            pre[((size_t)tt * G4_ + n) * B_ + bb] = acc[i][j] + bias[n];
        }
    }
}

// ---------------------------------------------------------------------------
// Wh (fp32 [2048][512]) -> hi/lo bf16 pair in MFMA-A-fragment order (R7/R8):
//   idx[wgin][w][ks][lane][e]; lane l: r=l&15 -> (g=r&3, j=wgin*16+w*4+(r>>2)),
//   k = ks*32 + (l>>4)*8 + e.
// ---------------------------------------------------------------------------
__global__ __launch_bounds__(256) void whb_k(
    const float* __restrict__ Wh,
    ushort* __restrict__ WhH, ushort* __restrict__ WhL)
{
    int i = blockIdx.x * 256 + threadIdx.x;       // 1,048,576
    int e = i & 7, l = (i >> 3) & 63, ks = (i >> 9) & 15;
    int w = (i >> 13) & 3, wgin = i >> 15;
    int r = l & 15, g = r & 3, j = wgin * 16 + w * 4 + (r >> 2);
    int k = ks * 32 + ((l >> 4) << 3) + e;
    float x = Wh[(size_t)(g * H_ + j) * H_ + k];
    ushort hi = f2bf(x);
    WhH[i] = hi;
    WhL[i] = f2bf(x - bf2f(hi));
}

// ---------------------------------------------------------------------------
// Persistent recurrence v8: R8 LDS staging revived as pure DMA + forced
// register-resident weights + producer-side hi/lo packing (R9 publish).
// grp = bid&7 (slab stays XCD-local; perf-only), wgin = bid>>3.
// Staging: 32 chunks of 1KB via global_load_lds with PRE-PERMUTED per-lane
// global source (slab [cc][k] -> frag [plane][ks][lane][8]); LDS dest linear
// -> no VALU, no LDS conflicts either side.
// MFMA: 48 per step (3 indep hi/lo chains), weights pinned in VGPRs by an
// opaque asm barrier (defeats R9's rematerialization).
// Protocol (first-touch slabs, relaxed agent cnt, write-through publish,
// vmcnt drain before signal) proven R4-R9.
// ---------------------------------------------------------------------------
__global__ __launch_bounds__(256, 1) void lstm_persist_k(
    const float* __restrict__ pre,    // [S][G4][B]
    const ushort* __restrict__ WhH,   // frag-ordered bf16 hi
    const ushort* __restrict__ WhL,   // frag-ordered bf16 lo
    ushort* __restrict__ hb,          // h slabs [S][8][2][16][512]
    unsigned* __restrict__ cnt)       // [8][S][16], zeroed before launch
{
    __shared__ ushort hS[16384];      // frag order: [plane(2)][ks(16)][lane(64)][8]

    const int tid  = threadIdx.x;
    const int grp  = blockIdx.x & 7;             // sync domain (XCD-local)
    const int wgin = blockIdx.x >> 3;            // 0..31 j-slice
    const int dir  = grp & 1;
    const int bblk = grp >> 1;
    const int w    = tid >> 6;                   // wave
    const int l    = tid & 63;
    const int ch   = l & 15;
    const int jloc = l >> 4;                     // 0..3
    const int j    = wgin * 16 + w * 4 + jloc;
    const int b    = bblk * 16 + ch;

    unsigned* mycnt = &cnt[((size_t)grp * S_) * 16];
    const ushort* wbaseH = WhH + ((size_t)(wgin * 4 + w) << 13) + (l << 3);
    const ushort* wbaseL = WhL + ((size_t)(wgin * 4 + w) << 13) + (l << 3);

    // per-lane permuted slab offset for DMA staging:
    //   frag(plane,ks,l,e) <- slab ushort idx plane*8192 + (l&15)*512
    //                         + ks*32 + (l>>4)*8 + e
    const int dmaLane = (l & 15) * 512 + ((l >> 4) << 3);

    // preload this wave's full weight slice and PIN it in VGPRs
    bf16x8 wH[16], wL[16];
#pragma unroll
    for (int ks = 0; ks < 16; ++ks) {
        wH[ks] = *(const bf16x8*)(wbaseH + (ks << 9));
        wL[ks] = *(const bf16x8*)(wbaseL + (ks << 9));
    }
#pragma unroll
    for (int ks = 0; ks < 16; ++ks) {
        asm volatile("" : "+v"(wH[ks]));
        asm volatile("" : "+v"(wL[ks]));
    }

    float c = 0.0f;

    for (int t = 0; t < S_; ++t) {
        const int tf = dir ? (S_ - 1 - t) : t;

        // own (j,b) pre values -> MFMA C-in (issued before the poll)
        f32x4 acc;
#pragma unroll
        for (int g = 0; g < 4; ++g)
            acc[g] = pre[((size_t)tf * G4_ + g * H_ + j) * B_ + b];

        if (t > 0) {
            // group barrier: poll (relaxed agent, no cache maintenance)
            unsigned guard = 0;
            while (__hip_atomic_load(&mycnt[(size_t)(t - 1) * 16], __ATOMIC_RELAXED,
                                     __HIP_MEMORY_SCOPE_AGENT) < 32u) {
                if (++guard > (1u << 18)) break;   // fail visibly, don't hang
            }

            // DMA-stage slab(t-1) -> LDS frag order (8 issues/wave)
            const int tfp = dir ? (tf + 1) : (tf - 1);
            const ushort* slab = hb + slab_off(tfp, grp);
#pragma unroll
            for (int i = 0; i < 8; ++i) {
                int cchunk = (w << 3) + i;            // 0..31
                int plane  = cchunk >> 4;
                int ks     = cchunk & 15;
                dma16(slab + plane * 8192 + ks * 32 + dmaLane,
                      hS + cchunk * 512);
            }
            asm volatile("s_waitcnt vmcnt(0)" ::: "memory");
            __syncthreads();

            // 48 MFMAs over K=512, 3 independent chains, B-frags from LDS
            f32x4 aB = {0.f, 0.f, 0.f, 0.f}, aC = {0.f, 0.f, 0.f, 0.f};
#pragma unroll
            for (int ks = 0; ks < 16; ++ks) {
                int ridx = (ks << 9) + (l << 3);
                bf16x8 bh = *(const bf16x8*)&hS[ridx];
                bf16x8 bl = *(const bf16x8*)&hS[8192 + ridx];
                acc = __builtin_amdgcn_mfma_f32_16x16x32_bf16(wH[ks], bh, acc, 0, 0, 0);
                aB  = __builtin_amdgcn_mfma_f32_16x16x32_bf16(wH[ks], bl, aB, 0, 0, 0);
                aC  = __builtin_amdgcn_mfma_f32_16x16x32_bf16(wL[ks], bh, aC, 0, 0, 0);
            }
#pragma unroll
            for (int g = 0; g < 4; ++g) acc[g] += aB[g] + aC[g];
        }

        // gates (order i,f,o,g), fully lane-local
        float si = fsigmoid(acc[0]);
        float sf = fsigmoid(acc[1]);
        float so = fsigmoid(acc[2]);
        float tg = ftanh_(acc[3]);
        c = fmaf(sf, c, si * tg);
        float h = so * ftanh_(c);

        // publish h as hi/lo bf16, packed k-pairs via lane partner (j ^ 1)
        ushort hi = f2bf(h);
        ushort lo = f2bf(h - bf2f(hi));
        unsigned hv = ((unsigned)lo << 16) | hi;
        unsigned pv = (unsigned)__shfl_xor((int)hv, 16);   // partner: j^1
        if ((jloc & 1) == 0) {
            unsigned hiPair = (hv & 0xFFFFu) | (pv << 16);
            unsigned loPair = (hv >> 16) | (pv & 0xFFFF0000u);
            unsigned* shW = (unsigned*)(hb + slab_off(tf, grp));
            size_t ui = (size_t)ch * 256 + (j >> 1);
            __hip_atomic_store(&shW[ui], hiPair, __ATOMIC_RELAXED,
                               __HIP_MEMORY_SCOPE_AGENT);
            __hip_atomic_store(&shW[(SLAB_ >> 1) + ui], loPair, __ATOMIC_RELAXED,
                               __HIP_MEMORY_SCOPE_AGENT);
        }
        asm volatile("s_waitcnt vmcnt(0)" ::: "memory");
        __syncthreads();    // also fences LDS reuse for next step's DMA
        if (tid == 0)
            __hip_atomic_fetch_add(&mycnt[(size_t)t * 16], 1u,
                                   __ATOMIC_RELAXED, __HIP_MEMORY_SCOPE_AGENT);
    }
}

// out[t][b][e] = (hiF+loF) + (hiB+loB) from slabs
__global__ __launch_bounds__(256) void t4_to_row_k(
    const ushort* __restrict__ hb, float* __restrict__ out)
{
    int i  = blockIdx.x * 256 + threadIdx.x;   // 2,097,152 float4 units
    int e4 = i & (E4_ - 1);
    int b  = (i >> 7) & 63;
    int t  = i >> 13;
    int cc = b & 15, bb = b >> 4;
    size_t e = (size_t)cc * 512 + e4 * 4;
    const ushort* pF = hb + slab_off(t, bb * 2 + 0) + e;
    const ushort* pB = hb + slab_off(t, bb * 2 + 1) + e;
    ushort4 hF = *(const ushort4*)pF;
    ushort4 lF = *(const ushort4*)(pF + SLAB_);
    ushort4 hB = *(const ushort4*)pB;
    ushort4 lB = *(const ushort4*)(pB + SLAB_);
    float4 v = make_float4(
        bf2f(hF.x) + bf2f(lF.x) + bf2f(hB.x) + bf2f(lB.x),
        bf2f(hF.y) + bf2f(lF.y) + bf2f(hB.y) + bf2f(lB.y),
        bf2f(hF.z) + bf2f(lF.z) + bf2f(hB.z) + bf2f(lB.z),
        bf2f(hF.w) + bf2f(lF.w) + bf2f(hB.w) + bf2f(lB.w));
    *(float4*)&out[((size_t)(t * B_ + b)) * E_ + e4 * 4] = v;
}

// tail [b][j] = h_fwd(tf=255) + h_bwd(tf=0)
__global__ __launch_bounds__(256) void tail_k(
    const ushort* __restrict__ hb, float* __restrict__ out2)
{
    int i = blockIdx.x * 256 + threadIdx.x;   // 32768
    int b = i >> 9, j = i & 511;
    int cc = b & 15, bb = b >> 4;
    const ushort* pF = hb + slab_off(255, bb * 2 + 0) + (size_t)cc * 512 + j;
    const ushort* pB = hb + slab_off(0,   bb * 2 + 1) + (size_t)cc * 512 + j;
    out2[i] = bf2f(pF[0]) + bf2f(pF[SLAB_]) + bf2f(pB[0]) + bf2f(pB[SLAB_]);
}

// ---------------------------------------------------------------------------
// Workspace (bytes):
//   pre : 128 MiB (fp32)   hb : 64 MiB (bf16 hi/lo slabs)
//   cnt : 128 KiB          WhH/WhL : 2+2 MiB
// total ~196.2 MiB
// ---------------------------------------------------------------------------
extern "C" void kernel_launch(void* const* d_in, const int* in_sizes, int n_in,
                              void* d_out, int out_size, void* d_ws, size_t ws_size,
                              hipStream_t stream) {
    const float* x    = (const float*)d_in[0];
    const float* Wi   = (const float*)d_in[1];
    const float* Wh   = (const float*)d_in[2];
    const float* bias = (const float*)d_in[3];
    float* out = (float*)d_out;

    float* ws  = (float*)d_ws;
    float* pre = ws;
    ushort* hb = (ushort*)(pre + (size_t)S_ * G4_ * B_);        // 33.5M ushorts
    unsigned* cnt = (unsigned*)(hb + (size_t)S_ * 8 * 2 * SLAB_);
    ushort* WhH = (ushort*)(cnt + (size_t)8 * S_ * 16);
    ushort* WhL = WhH + (size_t)1024 * 1024;

    for (int l = 0; l < NL_; ++l) {
        const float* wi_l = Wi + (size_t)l * G4_ * E_;
        const float* wh_l = Wh + (size_t)l * G4_ * H_;
        const float* b_l  = bias + (size_t)l * G4_;
        if (l == 0) pre_gemm_k<0><<<2048, 256, 0, stream>>>(x,  hb, wi_l, b_l, pre);
        else        pre_gemm_k<1><<<2048, 256, 0, stream>>>(x,  hb, wi_l, b_l, pre);
        whb_k<<<4096, 256, 0, stream>>>(wh_l, WhH, WhL);
        hipMemsetAsync(cnt, 0, (size_t)8 * S_ * 16 * sizeof(unsigned), stream);
        lstm_persist_k<<<256, 256, 0, stream>>>(pre, WhH, WhL, hb, cnt);
    }
    t4_to_row_k<<<8192, 256, 0, stream>>>(hb, out);
    tail_k<<<128, 256, 0, stream>>>(hb, out + (size_t)S_ * B_ * H_);
}

// Round 11
// 4813.346 us; speedup vs baseline: 1.9947x; 1.2080x over previous
//
#include <hip/hip_runtime.h>
#include <math.h>

#define S_  256
#define B_  64
#define E_  512
#define H_  512
#define G4_ 2048   // 4*H
#define NL_ 4
#define E4_ 128    // H/4

typedef __attribute__((ext_vector_type(8))) _Float16 f16x8;
typedef __attribute__((ext_vector_type(4))) float f32x4;

__device__ __forceinline__ float fsigmoid(float x) {
    return 1.0f / (1.0f + __expf(-x));
}
__device__ __forceinline__ float ftanh_(float x) {
    x = fminf(fmaxf(x, -15.0f), 15.0f);
    float e = __expf(2.0f * x);
    return (e - 1.0f) / (e + 1.0f);
}
__device__ __forceinline__ ushort f2h(float x) {      // RNE f32->fp16
    _Float16 h = (_Float16)x;
    return *(ushort*)&h;
}
__device__ __forceinline__ float h2f(ushort u) {
    _Float16 h = *(_Float16*)&u;
    return (float)h;
}

// async global->LDS, 16B per lane (lane i lands at lptr + i*16)
__device__ __forceinline__ void dma16(const ushort* g, ushort* l) {
    __builtin_amdgcn_global_load_lds(
        (const __attribute__((address_space(1))) unsigned*)g,
        (__attribute__((address_space(3))) unsigned*)l, 16, 0, 0);
}

// ---------------------------------------------------------------------------
// h-slab layout (fp16, single plane):
//   hb[t][grp(8)][cc(16)][k(512)] half     grp = bblk*2 + dir; cc = b&15; k = j
// ---------------------------------------------------------------------------
#define SLAB_ ((size_t)16 * 512)          // halves per (t,grp)
__device__ __forceinline__ size_t slab_off(int t, int grp) {
    return (size_t)(t * 8 + grp) * SLAB_;
}

// A-tile loader: T4=0 -> row-major [M][E]; T4=1 -> hF+hB from fp16 slabs
template<int T4>
__device__ __forceinline__ float4 ldA(const float* __restrict__ A,
                                      const ushort* __restrict__ hb,
                                      int m, int kk) {
    if constexpr (T4) {
        int t = m >> 6, b = m & 63, cc = b & 15, bb = b >> 4;
        size_t e = (size_t)cc * 512 + kk;
        ushort4 hF = *(const ushort4*)(hb + slab_off(t, bb * 2 + 0) + e);
        ushort4 hB = *(const ushort4*)(hb + slab_off(t, bb * 2 + 1) + e);
        return make_float4(h2f(hF.x) + h2f(hB.x), h2f(hF.y) + h2f(hB.y),
                           h2f(hF.z) + h2f(hB.z), h2f(hF.w) + h2f(hB.w));
    } else {
        return *(const float4*)&A[(size_t)m * E_ + kk];
    }
}

// pre[t][g][b] = sum_k In[t*64+b][k] * Wi[g][k] + bias[g]
#define BM_ 128
#define BN_ 128
#define BK_ 16

template<int T4>
__global__ __launch_bounds__(256) void pre_gemm_k(
    const float* __restrict__ In,
    const ushort* __restrict__ hb,
    const float* __restrict__ Wi,
    const float* __restrict__ bias,
    float* __restrict__ pre)
{
    __shared__ float As[BK_][BM_ + 4];
    __shared__ float Bs[BK_][BN_ + 4];

    const int tid = threadIdx.x;
    const int bx  = blockIdx.x;          // 0..2047
    const int m0  = (bx >> 4) * BM_;
    const int n0  = (bx & 15) * BN_;
    const int tx  = tid & 15;
    const int ty  = tid >> 4;
    const int lr  = tid >> 2;            // 0..63
    const int lc  = (tid & 3) << 2;      // 0,4,8,12

    float acc[8][8];
#pragma unroll
    for (int i = 0; i < 8; ++i)
#pragma unroll
        for (int j = 0; j < 8; ++j) acc[i][j] = 0.0f;

    for (int k0 = 0; k0 < E_; k0 += BK_) {
        float4 a0 = ldA<T4>(In, hb, m0 + lr,      k0 + lc);
        float4 a1 = ldA<T4>(In, hb, m0 + lr + 64, k0 + lc);
        float4 b0 = *(const float4*)&Wi[(size_t)(n0 + lr) * E_ + k0 + lc];
        float4 b1 = *(const float4*)&Wi[(size_t)(n0 + lr + 64) * E_ + k0 + lc];
        __syncthreads();
        As[lc + 0][lr] = a0.x; As[lc + 1][lr] = a0.y; As[lc + 2][lr] = a0.z; As[lc + 3][lr] = a0.w;
        As[lc + 0][lr + 64] = a1.x; As[lc + 1][lr + 64] = a1.y; As[lc + 2][lr + 64] = a1.z; As[lc + 3][lr + 64] = a1.w;
        Bs[lc + 0][lr] = b0.x; Bs[lc + 1][lr] = b0.y; Bs[lc + 2][lr] = b0.z; Bs[lc + 3][lr] = b0.w;
        Bs[lc + 0][lr + 64] = b1.x; Bs[lc + 1][lr + 64] = b1.y; Bs[lc + 2][lr + 64] = b1.z; Bs[lc + 3][lr + 64] = b1.w;
        __syncthreads();
#pragma unroll
        for (int kk = 0; kk < BK_; ++kk) {
            float4 av0 = *(const float4*)&As[kk][ty * 8];
            float4 av1 = *(const float4*)&As[kk][ty * 8 + 4];
            float4 bv0 = *(const float4*)&Bs[kk][tx * 8];
            float4 bv1 = *(const float4*)&Bs[kk][tx * 8 + 4];
            float a[8] = {av0.x, av0.y, av0.z, av0.w, av1.x, av1.y, av1.z, av1.w};
            float b[8] = {bv0.x, bv0.y, bv0.z, bv0.w, bv1.x, bv1.y, bv1.z, bv1.w};
#pragma unroll
            for (int i = 0; i < 8; ++i)
#pragma unroll
                for (int j = 0; j < 8; ++j)
                    acc[i][j] = fmaf(a[i], b[j], acc[i][j]);
        }
    }

#pragma unroll
    for (int i = 0; i < 8; ++i) {
        int m  = m0 + ty * 8 + i;
        int tt = m >> 6;
        int bb = m & 63;
#pragma unroll
        for (int j = 0; j < 8; ++j) {
            int n = n0 + tx * 8 + j;
            pre[((size_t)tt * G4_ + n) * B_ + bb] = acc[i][j] + bias[n];
        }
    }
}

// ---------------------------------------------------------------------------
// Wh (fp32 [2048][512]) -> fp16 in MFMA-A-fragment order (same map as R7-R10):
//   idx[wgin][w][ks][lane][e]; lane l: r=l&15 -> (g=r&3, j=wgin*16+w*4+(r>>2)),
//   k = ks*32 + (l>>4)*8 + e.
// ---------------------------------------------------------------------------
__global__ __launch_bounds__(256) void whf_k(
    const float* __restrict__ Wh, ushort* __restrict__ WhF)
{
    int i = blockIdx.x * 256 + threadIdx.x;       // 1,048,576
    int e = i & 7, l = (i >> 3) & 63, ks = (i >> 9) & 15;
    int w = (i >> 13) & 3, wgin = i >> 15;
    int r = l & 15, g = r & 3, j = wgin * 16 + w * 4 + (r >> 2);
    int k = ks * 32 + ((l >> 4) << 3) + e;
    WhF[i] = f2h(Wh[(size_t)(g * H_ + j) * H_ + k]);
}

// ---------------------------------------------------------------------------
// Persistent recurrence v9: single-fp16 MFMA + flag barrier.
// grp = bid&7 (XCD-local slab; perf-only), wgin = bid>>3. Per WG: 16 j-cols,
// wave w owns rows r=(jloc<<2)|g for j = wgin*16+w*4+jloc; lane-local gates.
// Weights: 16 x f16x8 = 64 VGPRs per wave, pinned via opaque asm.
// Per step: flag-poll (lane-parallel, __all) -> DMA 16KB slab->LDS frag order
// (4 issues/wave, pre-permuted global src) -> 16 MFMAs (2 chains) -> gates ->
// publish fp16 (1 store per lane pair, write-through) -> drain -> flag store.
// First-touch addresses per (t,grp) throughout; relaxed agent everywhere.
// ---------------------------------------------------------------------------
__global__ __launch_bounds__(256, 1) void lstm_persist_k(
    const float* __restrict__ pre,    // [S][G4][B]
    const ushort* __restrict__ WhF,   // frag-ordered fp16 weights
    ushort* __restrict__ hb,          // h slabs [S][8][16][512] fp16
    unsigned* __restrict__ flg)       // [8][S][32], zeroed before launch
{
    __shared__ ushort hS[8192];       // frag order: [ks(16)][lane(64)][8]

    const int tid  = threadIdx.x;
    const int grp  = blockIdx.x & 7;             // sync domain (XCD-local)
    const int wgin = blockIdx.x >> 3;            // 0..31 j-slice
    const int dir  = grp & 1;
    const int bblk = grp >> 1;
    const int w    = tid >> 6;                   // wave
    const int l    = tid & 63;
    const int ch   = l & 15;
    const int jloc = l >> 4;                     // 0..3
    const int j    = wgin * 16 + w * 4 + jloc;
    const int b    = bblk * 16 + ch;

    const ushort* wbase = WhF + ((size_t)(wgin * 4 + w) << 13) + (l << 3);
    // per-lane permuted slab offset: frag(ks,l,e) <- slab (l&15)*512 + ks*32
    //                                               + (l>>4)*8 + e
    const int dmaLane = (l & 15) * 512 + ((l >> 4) << 3);

    // preload this wave's weight slice (64 VGPRs) and pin it
    f16x8 wF[16];
#pragma unroll
    for (int ks = 0; ks < 16; ++ks)
        wF[ks] = *(const f16x8*)(wbase + (ks << 9));
#pragma unroll
    for (int ks = 0; ks < 16; ++ks)
        asm volatile("" : "+v"(wF[ks]));

    float c = 0.0f;

    for (int t = 0; t < S_; ++t) {
        const int tf = dir ? (S_ - 1 - t) : t;

        // own (j,b) pre values -> MFMA C-in (issued before the poll)
        f32x4 acc;
#pragma unroll
        for (int g = 0; g < 4; ++g)
            acc[g] = pre[((size_t)tf * G4_ + g * H_ + j) * B_ + b];

        if (t > 0) {
            // flag barrier: 32 per-WG flags, lane-parallel poll, one LLC
            // batch per iteration, no RMW contention
            const unsigned* fb = &flg[((size_t)grp * S_ + (t - 1)) * 32];
            unsigned guard = 0;
            for (;;) {
                unsigned f = __hip_atomic_load(&fb[l & 31], __ATOMIC_RELAXED,
                                               __HIP_MEMORY_SCOPE_AGENT);
                if (__all(f != 0)) break;
                if (++guard > (1u << 18)) break;   // fail visibly, don't hang
            }

            // DMA-stage slab(t-1) -> LDS frag order (4 issues/wave)
            const int tfp = dir ? (tf + 1) : (tf - 1);
            const ushort* slab = hb + slab_off(tfp, grp);
#pragma unroll
            for (int i = 0; i < 4; ++i) {
                int ks = (w << 2) + i;            // 0..15
                dma16(slab + ks * 32 + dmaLane, hS + ks * 512);
            }
            asm volatile("s_waitcnt vmcnt(0)" ::: "memory");
            __syncthreads();

            // 16 MFMAs over K=512, 2 interleaved chains
            f32x4 a1 = {0.f, 0.f, 0.f, 0.f};
#pragma unroll
            for (int ks = 0; ks < 16; ks += 2) {
                f16x8 b0 = *(const f16x8*)&hS[(ks << 9) + (l << 3)];
                f16x8 b1 = *(const f16x8*)&hS[((ks + 1) << 9) + (l << 3)];
                acc = __builtin_amdgcn_mfma_f32_16x16x32_f16(wF[ks], b0, acc, 0, 0, 0);
                a1  = __builtin_amdgcn_mfma_f32_16x16x32_f16(wF[ks + 1], b1, a1, 0, 0, 0);
            }
#pragma unroll
            for (int g = 0; g < 4; ++g) acc[g] += a1[g];
        }

        // gates (order i,f,o,g), fully lane-local
        float si = fsigmoid(acc[0]);
        float sf = fsigmoid(acc[1]);
        float so = fsigmoid(acc[2]);
        float tg = ftanh_(acc[3]);
        c = fmaf(sf, c, si * tg);
        float h = so * ftanh_(c);

        // publish h fp16, k-pair packed via lane partner (jloc ^ 1)
        unsigned hv = f2h(h);
        unsigned pv = (unsigned)__shfl_xor((int)hv, 16);   // partner lane l^16
        if ((jloc & 1) == 0) {
            unsigned pair = (hv & 0xFFFFu) | (pv << 16);
            unsigned* shW = (unsigned*)(hb + slab_off(tf, grp));
            __hip_atomic_store(&shW[(size_t)ch * 256 + (j >> 1)], pair,
                               __ATOMIC_RELAXED, __HIP_MEMORY_SCOPE_AGENT);
        }
        asm volatile("s_waitcnt vmcnt(0)" ::: "memory");
        __syncthreads();    // all waves drained; LDS reusable next step
        if (tid == 0)
            __hip_atomic_store(&flg[((size_t)grp * S_ + t) * 32 + wgin], 1u,
                               __ATOMIC_RELAXED, __HIP_MEMORY_SCOPE_AGENT);
    }
}

// out[t][b][e] = hF + hB from fp16 slabs
__global__ __launch_bounds__(256) void t4_to_row_k(
    const ushort* __restrict__ hb, float* __restrict__ out)
{
    int i  = blockIdx.x * 256 + threadIdx.x;   // 2,097,152 float4 units
    int e4 = i & (E4_ - 1);
    int b  = (i >> 7) & 63;
    int t  = i >> 13;
    int cc = b & 15, bb = b >> 4;
    size_t e = (size_t)cc * 512 + e4 * 4;
    ushort4 hF = *(const ushort4*)(hb + slab_off(t, bb * 2 + 0) + e);
    ushort4 hB = *(const ushort4*)(hb + slab_off(t, bb * 2 + 1) + e);
    float4 v = make_float4(h2f(hF.x) + h2f(hB.x), h2f(hF.y) + h2f(hB.y),
                           h2f(hF.z) + h2f(hB.z), h2f(hF.w) + h2f(hB.w));
    *(float4*)&out[((size_t)(t * B_ + b)) * E_ + e4 * 4] = v;
}

// tail [b][j] = h_fwd(tf=255) + h_bwd(tf=0)
__global__ __launch_bounds__(256) void tail_k(
    const ushort* __restrict__ hb, float* __restrict__ out2)
{
    int i = blockIdx.x * 256 + threadIdx.x;   // 32768
    int b = i >> 9, j = i & 511;
    int cc = b & 15, bb = b >> 4;
    ushort hF = hb[slab_off(255, bb * 2 + 0) + (size_t)cc * 512 + j];
    ushort hB = hb[slab_off(0,   bb * 2 + 1) + (size_t)cc * 512 + j];
    out2[i] = h2f(hF) + h2f(hB);
}

// ---------------------------------------------------------------------------
// Workspace (bytes):
//   pre : 128 MiB (fp32)   hb : 32 MiB (fp16 slabs [S][8][16][512])
//   flg : 256 KiB          WhF : 2 MiB
// total ~162 MiB
// ---------------------------------------------------------------------------
extern "C" void kernel_launch(void* const* d_in, const int* in_sizes, int n_in,
                              void* d_out, int out_size, void* d_ws, size_t ws_size,
                              hipStream_t stream) {
    const float* x    = (const float*)d_in[0];
    const float* Wi   = (const float*)d_in[1];
    const float* Wh   = (const float*)d_in[2];
    const float* bias = (const float*)d_in[3];
    float* out = (float*)d_out;

    float* ws  = (float*)d_ws;
    float* pre = ws;
    ushort* hb = (ushort*)(pre + (size_t)S_ * G4_ * B_);        // 16.8M ushorts
    unsigned* flg = (unsigned*)(hb + (size_t)S_ * 8 * SLAB_);   // 65536 u32
    ushort* WhF = (ushort*)(flg + (size_t)8 * S_ * 32);

    for (int l = 0; l < NL_; ++l) {
        const float* wi_l = Wi + (size_t)l * G4_ * E_;
        const float* wh_l = Wh + (size_t)l * G4_ * H_;
        const float* b_l  = bias + (size_t)l * G4_;
        if (l == 0) pre_gemm_k<0><<<2048, 256, 0, stream>>>(x,  hb, wi_l, b_l, pre);
        else        pre_gemm_k<1><<<2048, 256, 0, stream>>>(x,  hb, wi_l, b_l, pre);
        whf_k<<<4096, 256, 0, stream>>>(wh_l, WhF);
        hipMemsetAsync(flg, 0, (size_t)8 * S_ * 32 * sizeof(unsigned), stream);
        lstm_persist_k<<<256, 256, 0, stream>>>(pre, WhF, hb, flg);
    }
    t4_to_row_k<<<8192, 256, 0, stream>>>(hb, out);
    tail_k<<<128, 256, 0, stream>>>(hb, out + (size_t)S_ * B_ * H_);
}

// Round 12
// 3317.359 us; speedup vs baseline: 2.8942x; 1.4510x over previous
//
#include <hip/hip_runtime.h>
#include <math.h>

#define S_  256
#define B_  64
#define E_  512
#define H_  512
#define G4_ 2048   // 4*H
#define NL_ 4
#define E4_ 128    // H/4

typedef __attribute__((ext_vector_type(8))) _Float16 f16x8;
typedef __attribute__((ext_vector_type(4))) float f32x4;

__device__ __forceinline__ float fsigmoid(float x) {
    return 1.0f / (1.0f + __expf(-x));
}
__device__ __forceinline__ float ftanh_(float x) {
    x = fminf(fmaxf(x, -15.0f), 15.0f);
    float e = __expf(2.0f * x);
    return (e - 1.0f) / (e + 1.0f);
}
__device__ __forceinline__ ushort f2h(float x) {      // RNE f32->fp16
    _Float16 h = (_Float16)x;
    return *(ushort*)&h;
}
__device__ __forceinline__ float h2f(ushort u) {
    _Float16 h = *(_Float16*)&u;
    return (float)h;
}

// async global->LDS, 16B per lane (lane i lands at lptr + i*16)
__device__ __forceinline__ void dma16(const ushort* g, ushort* l) {
    __builtin_amdgcn_global_load_lds(
        (const __attribute__((address_space(1))) unsigned*)g,
        (__attribute__((address_space(3))) unsigned*)l, 16, 0, 0);
}

// ---------------------------------------------------------------------------
// h-slab layout (fp16):
//   hb[t][grp(8)][cc(16)][k(512)] half     grp = bblk*2 + dir; cc = b&15; k = j
// ---------------------------------------------------------------------------
#define SLAB_ ((size_t)16 * 512)          // halves per (t,grp)
__device__ __forceinline__ size_t slab_off(int t, int grp) {
    return (size_t)(t * 8 + grp) * SLAB_;
}

// ---------------------------------------------------------------------------
// Frag-order conversions. All use the verified 16x16x32 fragment maps:
//   A-frag (16 rows x 32 k): lane l -> row = base + (l&15), k = ks*32+(l>>4)*8+e
//   B-frag (32 k x 16 cols): lane l -> col = base + (l&15), same k map
// Layouts: WiF/WhF [RT][ks(16)][l(64)][e(8)]; inF [MT(1024)][ks(16)][l(64)][e(8)]
// ---------------------------------------------------------------------------

// Wi fp32 [2048][512] -> WiF fp16 frag order, plain row tiles (128 tiles of 16)
__global__ __launch_bounds__(256) void wif_k(
    const float* __restrict__ Wi, ushort* __restrict__ WiF)
{
    int i = blockIdx.x * 256 + threadIdx.x;   // 131,072
    int nt = i >> 10, ks = (i >> 6) & 15, l = i & 63;
    int n = nt * 16 + (l & 15);
    int k = ks * 32 + ((l >> 4) << 3);
    const float* src = Wi + (size_t)n * E_ + k;
    float4 v0 = *(const float4*)src, v1 = *(const float4*)(src + 4);
    ushort o[8] = {f2h(v0.x), f2h(v0.y), f2h(v0.z), f2h(v0.w),
                   f2h(v1.x), f2h(v1.y), f2h(v1.z), f2h(v1.w)};
    *(ushort4*)(WiF + (size_t)i * 8)     = *(ushort4*)&o[0];
    *(ushort4*)(WiF + (size_t)i * 8 + 4) = *(ushort4*)&o[4];
}

// Wh fp32 -> WhF fp16, gate-interleaved rows r=(jloc<<2)|g (persist A order)
__global__ __launch_bounds__(256) void whf_k(
    const float* __restrict__ Wh, ushort* __restrict__ WhF)
{
    int i = blockIdx.x * 256 + threadIdx.x;       // 1,048,576
    int e = i & 7, l = (i >> 3) & 63, ks = (i >> 9) & 15;
    int w = (i >> 13) & 3, wgin = i >> 15;
    int r = l & 15, g = r & 3, j = wgin * 16 + w * 4 + (r >> 2);
    int k = ks * 32 + ((l >> 4) << 3) + e;
    WhF[i] = f2h(Wh[(size_t)(g * H_ + j) * H_ + k]);
}

// layer-0 input: x fp32 [16384][512] -> inF fp16 B-frag order
__global__ __launch_bounds__(256) void cvt_x_k(
    const float* __restrict__ x, ushort* __restrict__ inF)
{
    int i = blockIdx.x * 256 + threadIdx.x;   // 1,048,576
    int mt = i >> 10, ks = (i >> 6) & 15, l = i & 63;
    int m = mt * 16 + (l & 15);
    int k = ks * 32 + ((l >> 4) << 3);
    const float* src = x + (size_t)m * E_ + k;
    float4 v0 = *(const float4*)src, v1 = *(const float4*)(src + 4);
    ushort o[8] = {f2h(v0.x), f2h(v0.y), f2h(v0.z), f2h(v0.w),
                   f2h(v1.x), f2h(v1.y), f2h(v1.z), f2h(v1.w)};
    *(ushort4*)(inF + (size_t)i * 8)     = *(ushort4*)&o[0];
    *(ushort4*)(inF + (size_t)i * 8 + 4) = *(ushort4*)&o[4];
}

// layer>=1 input: inF = hsF + hsB from fp16 slabs
__global__ __launch_bounds__(256) void cvt_hs_k(
    const ushort* __restrict__ hb, ushort* __restrict__ inF)
{
    int i = blockIdx.x * 256 + threadIdx.x;   // 1,048,576
    int mt = i >> 10, ks = (i >> 6) & 15, l = i & 63;
    int m = mt * 16 + (l & 15);
    int k = ks * 32 + ((l >> 4) << 3);
    int t = m >> 6, b = m & 63, cc = b & 15, bb = b >> 4;
    const ushort* pF = hb + slab_off(t, bb * 2 + 0) + (size_t)cc * 512 + k;
    const ushort* pB = hb + slab_off(t, bb * 2 + 1) + (size_t)cc * 512 + k;
    ushort4 f0 = *(const ushort4*)pF, f1 = *(const ushort4*)(pF + 4);
    ushort4 b0 = *(const ushort4*)pB, b1 = *(const ushort4*)(pB + 4);
    ushort o[8] = {f2h(h2f(f0.x) + h2f(b0.x)), f2h(h2f(f0.y) + h2f(b0.y)),
                   f2h(h2f(f0.z) + h2f(b0.z)), f2h(h2f(f0.w) + h2f(b0.w)),
                   f2h(h2f(f1.x) + h2f(b1.x)), f2h(h2f(f1.y) + h2f(b1.y)),
                   f2h(h2f(f1.z) + h2f(b1.z)), f2h(h2f(f1.w) + h2f(b1.w))};
    *(ushort4*)(inF + (size_t)i * 8)     = *(ushort4*)&o[0];
    *(ushort4*)(inF + (size_t)i * 8 + 4) = *(ushort4*)&o[4];
}

// ---------------------------------------------------------------------------
// pre = Wi . in + bias via fp16 MFMA.  C[n(2048)][m(16384)], K=512.
// Grid 2048 WGs: nb = bid>>6 (32 x 64n), mb = bid&63 (64 x 256m).
// Wave w owns m-quarter; per wave 4 n-tiles x 4 m-tiles, 256 MFMAs.
// Output: pre[t][n][b] with t = m>>6, b = m&63 (fp32 + bias).
// ---------------------------------------------------------------------------
__global__ __launch_bounds__(256) void gemm_mfma_k(
    const ushort* __restrict__ WiF,
    const ushort* __restrict__ inF,
    const float* __restrict__ bias,
    float* __restrict__ pre)
{
    const int tid = threadIdx.x;
    const int w   = tid >> 6;
    const int l   = tid & 63;
    const int nb  = blockIdx.x >> 6;
    const int mb  = blockIdx.x & 63;

    f32x4 acc[4][4];
#pragma unroll
    for (int i = 0; i < 4; ++i)
#pragma unroll
        for (int j = 0; j < 4; ++j) acc[i][j] = f32x4{0.f, 0.f, 0.f, 0.f};

    const ushort* aB = WiF + ((size_t)(nb * 4) * 16) * 512 + l * 8;
    const ushort* bB = inF + ((size_t)(mb * 16 + w * 4) * 16) * 512 + l * 8;

    for (int ks = 0; ks < 16; ++ks) {
        f16x8 af[4], bf[4];
#pragma unroll
        for (int i = 0; i < 4; ++i)
            af[i] = *(const f16x8*)(aB + ((size_t)i * 16 + ks) * 512);
#pragma unroll
        for (int j = 0; j < 4; ++j)
            bf[j] = *(const f16x8*)(bB + ((size_t)j * 16 + ks) * 512);
#pragma unroll
        for (int i = 0; i < 4; ++i)
#pragma unroll
            for (int j = 0; j < 4; ++j)
                acc[i][j] = __builtin_amdgcn_mfma_f32_16x16x32_f16(
                    af[i], bf[j], acc[i][j], 0, 0, 0);
    }

#pragma unroll
    for (int i = 0; i < 4; ++i) {
#pragma unroll
        for (int j = 0; j < 4; ++j) {
#pragma unroll
            for (int g = 0; g < 4; ++g) {
                int n = nb * 64 + i * 16 + ((l >> 4) << 2) + g;
                int m = mb * 256 + w * 64 + j * 16 + (l & 15);
                int t = m >> 6, b = m & 63;
                pre[((size_t)t * G4_ + n) * B_ + b] = acc[i][j][g] + bias[n];
            }
        }
    }
}

// ---------------------------------------------------------------------------
// Persistent recurrence v10 (R11 + true weight pinning).
// grp = bid&7 (XCD-local slab; perf-only), wgin = bid>>3; 16 j/WG; wave w
// owns rows r=(jloc<<2)|g, lane-local gates/c. Flag barrier (lane-parallel
// poll). DMA slab->LDS frag order. 16 fp16 MFMAs / step. The "+v" pins INSIDE
// the t-loop make rematerialization of the weight loads illegal -> the 64
// weight VGPRs stay live (fixes R11's VGPR_Count=60 reload-from-L2).
// ---------------------------------------------------------------------------
__global__ __launch_bounds__(256, 1) void lstm_persist_k(
    const float* __restrict__ pre,    // [S][G4][B]
    const ushort* __restrict__ WhF,   // frag-ordered fp16 weights
    ushort* __restrict__ hb,          // h slabs [S][8][16][512] fp16
    unsigned* __restrict__ flg)       // [8][S][32], zeroed before launch
{
    __shared__ ushort hS[8192];       // frag order: [ks(16)][lane(64)][8]

    const int tid  = threadIdx.x;
    const int grp  = blockIdx.x & 7;             // sync domain (XCD-local)
    const int wgin = blockIdx.x >> 3;            // 0..31 j-slice
    const int dir  = grp & 1;
    const int bblk = grp >> 1;
    const int w    = tid >> 6;                   // wave
    const int l    = tid & 63;
    const int ch   = l & 15;
    const int jloc = l >> 4;                     // 0..3
    const int j    = wgin * 16 + w * 4 + jloc;
    const int b    = bblk * 16 + ch;

    const ushort* wbase = WhF + ((size_t)(wgin * 4 + w) << 13) + (l << 3);
    // per-lane permuted slab offset: frag(ks,l,e) <- slab (l&15)*512 + ks*32
    //                                               + (l>>4)*8 + e
    const int dmaLane = (l & 15) * 512 + ((l >> 4) << 3);

    // preload this wave's weight slice (64 VGPRs)
    f16x8 wF[16];
#pragma unroll
    for (int ks = 0; ks < 16; ++ks)
        wF[ks] = *(const f16x8*)(wbase + (ks << 9));

    float c = 0.0f;

    for (int t = 0; t < S_; ++t) {
        // opaque per-iteration redefinition: weights MUST stay in registers
#pragma unroll
        for (int ks = 0; ks < 16; ++ks)
            asm volatile("" : "+v"(wF[ks]));

        const int tf = dir ? (S_ - 1 - t) : t;

        // own (j,b) pre values -> MFMA C-in (issued before the poll)
        f32x4 acc;
#pragma unroll
        for (int g = 0; g < 4; ++g)
            acc[g] = pre[((size_t)tf * G4_ + g * H_ + j) * B_ + b];

        if (t > 0) {
            // flag barrier: 32 per-WG flags, lane-parallel poll
            const unsigned* fb = &flg[((size_t)grp * S_ + (t - 1)) * 32];
            unsigned guard = 0;
            for (;;) {
                unsigned f = __hip_atomic_load(&fb[l & 31], __ATOMIC_RELAXED,
                                               __HIP_MEMORY_SCOPE_AGENT);
                if (__all(f != 0)) break;
                if (++guard > (1u << 18)) break;   // fail visibly, don't hang
            }

            // DMA-stage slab(t-1) -> LDS frag order (4 issues/wave)
            const int tfp = dir ? (tf + 1) : (tf - 1);
            const ushort* slab = hb + slab_off(tfp, grp);
#pragma unroll
            for (int i = 0; i < 4; ++i) {
                int ks = (w << 2) + i;            // 0..15
                dma16(slab + ks * 32 + dmaLane, hS + ks * 512);
            }
            asm volatile("s_waitcnt vmcnt(0)" ::: "memory");
            __syncthreads();

            // 16 MFMAs over K=512, 2 interleaved chains
            f32x4 a1 = {0.f, 0.f, 0.f, 0.f};
#pragma unroll
            for (int ks = 0; ks < 16; ks += 2) {
                f16x8 b0 = *(const f16x8*)&hS[(ks << 9) + (l << 3)];
                f16x8 b1 = *(const f16x8*)&hS[((ks + 1) << 9) + (l << 3)];
                acc = __builtin_amdgcn_mfma_f32_16x16x32_f16(wF[ks], b0, acc, 0, 0, 0);
                a1  = __builtin_amdgcn_mfma_f32_16x16x32_f16(wF[ks + 1], b1, a1, 0, 0, 0);
            }
#pragma unroll
            for (int g = 0; g < 4; ++g) acc[g] += a1[g];
        }

        // gates (order i,f,o,g), fully lane-local
        float si = fsigmoid(acc[0]);
        float sf = fsigmoid(acc[1]);
        float so = fsigmoid(acc[2]);
        float tg = ftanh_(acc[3]);
        c = fmaf(sf, c, si * tg);
        float h = so * ftanh_(c);

        // publish h fp16, k-pair packed via lane partner (jloc ^ 1)
        unsigned hv = f2h(h);
        unsigned pv = (unsigned)__shfl_xor((int)hv, 16);   // partner lane l^16
        if ((jloc & 1) == 0) {
            unsigned pair = (hv & 0xFFFFu) | (pv << 16);
            unsigned* shW = (unsigned*)(hb + slab_off(tf, grp));
            __hip_atomic_store(&shW[(size_t)ch * 256 + (j >> 1)], pair,
                               __ATOMIC_RELAXED, __HIP_MEMORY_SCOPE_AGENT);
        }
        asm volatile("s_waitcnt vmcnt(0)" ::: "memory");
        __syncthreads();    // all waves drained; LDS reusable next step
        if (tid == 0)
            __hip_atomic_store(&flg[((size_t)grp * S_ + t) * 32 + wgin], 1u,
                               __ATOMIC_RELAXED, __HIP_MEMORY_SCOPE_AGENT);
    }
}

// out[t][b][e] = hF + hB from fp16 slabs
__global__ __launch_bounds__(256) void t4_to_row_k(
    const ushort* __restrict__ hb, float* __restrict__ out)
{
    int i  = blockIdx.x * 256 + threadIdx.x;   // 2,097,152 float4 units
    int e4 = i & (E4_ - 1);
    int b  = (i >> 7) & 63;
    int t  = i >> 13;
    int cc = b & 15, bb = b >> 4;
    size_t e = (size_t)cc * 512 + e4 * 4;
    ushort4 hF = *(const ushort4*)(hb + slab_off(t, bb * 2 + 0) + e);
    ushort4 hB = *(const ushort4*)(hb + slab_off(t, bb * 2 + 1) + e);
    float4 v = make_float4(h2f(hF.x) + h2f(hB.x), h2f(hF.y) + h2f(hB.y),
                           h2f(hF.z) + h2f(hB.z), h2f(hF.w) + h2f(hB.w));
    *(float4*)&out[((size_t)(t * B_ + b)) * E_ + e4 * 4] = v;
}

// tail [b][j] = h_fwd(tf=255) + h_bwd(tf=0)
__global__ __launch_bounds__(256) void tail_k(
    const ushort* __restrict__ hb, float* __restrict__ out2)
{
    int i = blockIdx.x * 256 + threadIdx.x;   // 32768
    int b = i >> 9, j = i & 511;
    int cc = b & 15, bb = b >> 4;
    ushort hF = hb[slab_off(255, bb * 2 + 0) + (size_t)cc * 512 + j];
    ushort hB = hb[slab_off(0,   bb * 2 + 1) + (size_t)cc * 512 + j];
    out2[i] = h2f(hF) + h2f(hB);
}

// ---------------------------------------------------------------------------
// Workspace (bytes):
//   pre : 128 MiB (fp32)   hb : 32 MiB   flg : 256 KiB
//   WhF : 2 MiB   WiF : 2 MiB   inF : 16 MiB       total ~180.3 MiB
// ---------------------------------------------------------------------------
extern "C" void kernel_launch(void* const* d_in, const int* in_sizes, int n_in,
                              void* d_out, int out_size, void* d_ws, size_t ws_size,
                              hipStream_t stream) {
    const float* x    = (const float*)d_in[0];
    const float* Wi   = (const float*)d_in[1];
    const float* Wh   = (const float*)d_in[2];
    const float* bias = (const float*)d_in[3];
    float* out = (float*)d_out;

    float* ws  = (float*)d_ws;
    float* pre = ws;
    ushort* hb = (ushort*)(pre + (size_t)S_ * G4_ * B_);        // 16.8M halves
    unsigned* flg = (unsigned*)(hb + (size_t)S_ * 8 * SLAB_);   // 65536 u32
    ushort* WhF = (ushort*)(flg + (size_t)8 * S_ * 32);
    ushort* WiF = WhF + (size_t)1024 * 1024;
    ushort* inF = WiF + (size_t)1024 * 1024;

    for (int l = 0; l < NL_; ++l) {
        const float* wi_l = Wi + (size_t)l * G4_ * E_;
        const float* wh_l = Wh + (size_t)l * G4_ * H_;
        const float* b_l  = bias + (size_t)l * G4_;
        if (l == 0) cvt_x_k<<<4096, 256, 0, stream>>>(x, inF);
        else        cvt_hs_k<<<4096, 256, 0, stream>>>(hb, inF);
        wif_k<<<512, 256, 0, stream>>>(wi_l, WiF);
        gemm_mfma_k<<<2048, 256, 0, stream>>>(WiF, inF, b_l, pre);
        whf_k<<<4096, 256, 0, stream>>>(wh_l, WhF);
        hipMemsetAsync(flg, 0, (size_t)8 * S_ * 32 * sizeof(unsigned), stream);
        lstm_persist_k<<<256, 256, 0, stream>>>(pre, WhF, hb, flg);
    }
    t4_to_row_k<<<8192, 256, 0, stream>>>(hb, out);
    tail_k<<<128, 256, 0, stream>>>(hb, out + (size_t)S_ * B_ * H_);
}